// Round 11
// baseline (90.697 us; speedup 1.0000x reference)
//
#include <hip/hip_runtime.h>
#include <math.h>

#define BATCH_  256
#define NTOT    16384
#define ETOT    524288

typedef __attribute__((ext_vector_type(8))) short short8v;
typedef __attribute__((ext_vector_type(4))) float f32x4;

#define MFMA16(a,b,c) __builtin_amdgcn_mfma_f32_16x16x32_bf16((a),(b),(c),0,0,0)

__device__ __forceinline__ unsigned short f2bf(float f) {
    unsigned int x = __float_as_uint(f);
    return (unsigned short)((x + 0x7fffu + ((x >> 16) & 1u)) >> 16);
}
__device__ __forceinline__ float bf2f(unsigned short h) {
    return __uint_as_float(((unsigned int)h) << 16);
}
__device__ __forceinline__ float softplus_f(float v) {
    return v > 20.f ? v : log1pf(expf(v));
}
__device__ __forceinline__ float dot4(f32x4 a, f32x4 b) {
    float z = a[0] * b[0];
    z = fmaf(a[1], b[1], z);
    z = fmaf(a[2], b[2], z);
    z = fmaf(a[3], b[3], z);
    return z;
}
__device__ __forceinline__ void packfrag(f32x4 a, f32x4 q, short8v& hi, short8v& lo) {
    float v[8] = {a[0], a[1], a[2], a[3], q[0], q[1], q[2], q[3]};
#pragma unroll
    for (int j = 0; j < 8; j++) {
        const unsigned short h = f2bf(v[j]);
        hi[j] = (short)h;
        lo[j] = (short)f2bf(v[j] - bf2f(h));
    }
}
// hi-only pack via HW packed converter (RNE), 4 VALU for 8 values
__device__ __forceinline__ short8v cvthi8(f32x4 a, f32x4 q) {
    union { short8v s; unsigned int u[4]; } r;
    asm("v_cvt_pk_bf16_f32 %0, %1, %2" : "=v"(r.u[0]) : "v"(a[0]), "v"(a[1]));
    asm("v_cvt_pk_bf16_f32 %0, %1, %2" : "=v"(r.u[1]) : "v"(a[2]), "v"(a[3]));
    asm("v_cvt_pk_bf16_f32 %0, %1, %2" : "=v"(r.u[2]) : "v"(q[0]), "v"(q[1]));
    asm("v_cvt_pk_bf16_f32 %0, %1, %2" : "=v"(r.u[3]) : "v"(q[2]), "v"(q[3]));
    return r.s;
}

// ---------------------------------------------------------------------------
// K0: pre-pack split-bf16 (hi/lo) MFMA A-fragments of W1 (160x256, kt 0..4)
// and W2 (256x256, kt 0..7). Unit u = kt*16 + cht (W1: u 0..79; W2: u 80..207):
// frags[u*1024 + hl*512 + l*8 + j] = W[(kt*32+(l>>4)*8+j)*256 + cht*16+(l&15)]
// ---------------------------------------------------------------------------
__global__ __launch_bounds__(256) void k_prep(const float* __restrict__ W1,
                                              const float* __restrict__ W2,
                                              unsigned short* __restrict__ frags) {
    const int u = blockIdx.x;
    const float* S = (u < 80) ? W1 : W2;
    const int ul = (u < 80) ? u : (u - 80);
    const int rowbase = (ul >> 4) * 32;
    const int cht = ul & 15;
    for (int idx = threadIdx.x; idx < 512; idx += 256) {
        const int l = idx >> 3, j = idx & 7;
        const int row = rowbase + ((l >> 4) << 3) + j;
        const int col = cht * 16 + (l & 15);
        const float v = S[row * 256 + col];
        const unsigned short h = f2bf(v);
        frags[u * 1024 + idx]       = h;
        frags[u * 1024 + 512 + idx] = f2bf(v - bf2f(h));
    }
}

// ---------------------------------------------------------------------------
// K1: phases A+B per (batch, channel-half, offset-half). Grid 1024:
// b = bx&255, half = (bx>>8)&1, oh = bx>>9 (b-major keeps related blocks on
// one XCD for shared ea/x L2 hits).
// 512 thr, 8 waves, waves_per_eu(2). LDS 50 KB -> 3 blocks/CU resident
// (round-10 limiter was residency: 67.5 KB gave 1 block, occupancy 19.5%).
// Each block: 16 offsets = 8 chunks x 2 offsets, dbuf hi-only bf16 ea,
// 2-term split MFMA, partial relu-sum -> sumh1 part[oh].
// LDS: s_xwb[64][128] f32 swz (32K) | s_ea [2][2][4][64][8] bf16 (16K) | dst 2K.
// ---------------------------------------------------------------------------
__global__ __launch_bounds__(512) __attribute__((amdgpu_waves_per_eu(2)))
void k_ab4(
    const float* __restrict__ x, const float* __restrict__ ea,
    const int* __restrict__ dst, const float* __restrict__ b1,
    const unsigned short* __restrict__ frags, float* __restrict__ sumh1)
{
    __shared__ __align__(16) unsigned char smem[51200];
    float*          s_xwb  = (float*)smem;                    // [64][128]
    unsigned short* s_ea   = (unsigned short*)(smem + 32768); // [2][2][4][64][8]
    unsigned char*  s_dstl = (unsigned char*)(smem + 49152);  // [2048]

    const int bx = blockIdx.x;
    const int b = bx & 255, half = (bx >> 8) & 1, oh = bx >> 9;
    const int tid = threadIdx.x;
    const int l = tid & 63, w = tid >> 6, g = l >> 4, l15 = l & 15;
    const int ng = w & 3, cqq = w >> 2;          // cqq in {0,1}
    const int node = ng * 16 + l15;
    const int swzn = (l15 & 7) << 2;

    // ---- dst staging (local ids, 1 byte per edge)
    for (int idx = tid; idx < 2048; idx += 512)
        s_dstl[idx] = (unsigned char)(dst[b * 2048 + idx] & 63);

    // ---- ea staging geometry: chunk = 2 offsets (64 floats/node);
    // thread -> (node sns, offset-in-chunk so, k-octet ko): 8 floats each.
    const int sns = tid >> 3;              // node 0..63
    const int so  = (tid & 7) >> 2;        // offset-in-chunk 0..1
    const int ko  = tid & 3;               // k-octet 0..3
    const int snl = sns & 15, ssng = sns >> 4;
    const float* seab = ea + (size_t)b * 65536 + (size_t)sns * 1024
                           + (oh * 16 + so) * 32 + ko * 8;

    // prologue: load chunk 0 (8 floats)
    f32x4 L0 = *(const f32x4*)(seab);
    f32x4 L1 = *(const f32x4*)(seab + 4);

    // ================= phase A =================
    short8v Xh[2], Xl[2];
#pragma unroll
    for (int kt = 0; kt < 2; kt++) {
        const float* p = x + (size_t)(b * 64 + node) * 64 + kt * 32 + g * 8;
        packfrag(*(const f32x4*)p, *(const f32x4*)(p + 4), Xh[kt], Xl[kt]);
    }

    f32x4 xab1[4];
#pragma unroll
    for (int i = 0; i < 4; i++) {
        const int cht = half * 8 + cqq * 4 + i;
        f32x4 d = *(const f32x4*)&b1[cht * 16 + g * 4];   // C-init = b1
#pragma unroll
        for (int kt = 0; kt < 2; kt++) {
            const int base = (kt * 16 + cht) * 1024 + l * 8;
            const short8v Ahh = *(const short8v*)&frags[base];
            const short8v All = *(const short8v*)&frags[base + 512];
            d = MFMA16(All, Xh[kt], d);
            d = MFMA16(Ahh, Xl[kt], d);
            d = MFMA16(Ahh, Xh[kt], d);
        }
        xab1[i] = d;
    }

#pragma unroll
    for (int i = 0; i < 4; i++) {
        const int cht = half * 8 + cqq * 4 + i;
        f32x4 d = {0.f, 0.f, 0.f, 0.f};
#pragma unroll
        for (int kt = 0; kt < 2; kt++) {
            const int base = ((kt + 2) * 16 + cht) * 1024 + l * 8;
            const short8v Ahh = *(const short8v*)&frags[base];
            const short8v All = *(const short8v*)&frags[base + 512];
            d = MFMA16(All, Xh[kt], d);
            d = MFMA16(Ahh, Xl[kt], d);
            d = MFMA16(Ahh, Xh[kt], d);
        }
        *(f32x4*)&s_xwb[node * 128 + (((cqq * 4 + i) * 16 + g * 4) ^ swzn)] = d;
    }

    // W1c A-frags (units 64..79), register-cached
    short8v Ah[4], Al[4];
#pragma unroll
    for (int i = 0; i < 4; i++) {
        const int base = (64 + half * 8 + cqq * 4 + i) * 1024 + l * 8;
        Ah[i] = *(const short8v*)&frags[base];
        Al[i] = *(const short8v*)&frags[base + 512];
    }

    // stage chunk 0 into buf 0; issue chunk 1 loads
    *(short8v*)&s_ea[((0 * 2 + so) * 4 + ssng) * 512 + (ko * 16 + snl) * 8]
        = cvthi8(L0, L1);
    L0 = *(const f32x4*)(seab + 64);
    L1 = *(const f32x4*)(seab + 68);
    __syncthreads();   // xwb + dstl + chunk0 visible

    f32x4 acc[4];
#pragma unroll
    for (int i = 0; i < 4; i++) acc[i] = (f32x4){0.f, 0.f, 0.f, 0.f};

    // ================= phase B ================= (8 chunks x 2 offsets)
    for (int c = 0; c < 8; ++c) {
        if (c < 7) {   // stage next chunk into other buffer
            const int nb = (c + 1) & 1;
            *(short8v*)&s_ea[((nb * 2 + so) * 4 + ssng) * 512 + (ko * 16 + snl) * 8]
                = cvthi8(L0, L1);
            if (c < 6) {
                const float* q = seab + (size_t)(c + 2) * 64;
                L0 = *(const f32x4*)(q);
                L1 = *(const f32x4*)(q + 4);
            }
        }

        const int cb = c & 1;
        const unsigned short dwc =
            *(const unsigned short*)&s_dstl[node * 32 + oh * 16 + c * 2];

#pragma unroll
        for (int ol = 0; ol < 2; ol++) {
            const short8v Bh =
                *(const short8v*)&s_ea[((cb * 2 + ol) * 4 + ng) * 512 + l * 8];
            const int d = (dwc >> (ol * 8)) & 63;
            const int swz = (d & 7) << 2;

#pragma unroll
            for (int i = 0; i < 4; i++) {
                const int cbl = (cqq * 4 + i) * 16 + g * 4;
                const f32x4 wb = *(const f32x4*)&s_xwb[d * 128 + (cbl ^ swz)];
                f32x4 di = MFMA16(Al[i], Bh, xab1[i]);   // 2-term split
                di = MFMA16(Ah[i], Bh, di);
#pragma unroll
                for (int r = 0; r < 4; r++)
                    acc[i][r] += fmaxf(di[r] + wb[r], 0.f);
            }
        }
        __syncthreads();   // chunk consumed; next-buf stores visible
    }

    // write partial sumh1 (part oh), linear [node][256]
    float* outp = sumh1 + (size_t)oh * NTOT * 256 + ((size_t)b * 64 + node) * 256;
#pragma unroll
    for (int i = 0; i < 4; i++) {
        const int cg = (half * 8 + cqq * 4 + i) * 16 + g * 4;
        *(f32x4*)&outp[cg] = acc[i];
    }
}

// ---------------------------------------------------------------------------
// K2: phases C+D per batch. 256 blocks, 1024 thr (16 waves).
// Stage sumh1 = part0+part1 -> LDS swizzled; C: agg = sumh1@W2 + 32*b2;
// stage head weights -> LDS; D: factored u/v dots; heads -> out.
// ---------------------------------------------------------------------------
__global__ __launch_bounds__(1024) __attribute__((amdgpu_waves_per_eu(2)))
void k_cd2(
    const float* __restrict__ x, const float* __restrict__ sumh1,
    const int* __restrict__ edges, const float* __restrict__ high,
    const unsigned short* __restrict__ frags, const float* __restrict__ b2,
    const float* __restrict__ Wmu,  const float* __restrict__ bmu,
    const float* __restrict__ Wsig, const float* __restrict__ bsig,
    const float* __restrict__ Wmu2, const float* __restrict__ bmu2,
    const float* __restrict__ Wsig2,const float* __restrict__ bsig2,
    float* __restrict__ out)
{
    __shared__ __align__(16) unsigned char smem[131072];
    float* s_sumh1 = (float*)smem;             // [64][256] swizzled
    float* s_agg   = (float*)(smem + 65536);   // [64][256] swizzled
    float* s_su    = (float*)smem;             // [64][4]   (after C)
    float* s_su2   = (float*)(smem + 1024);    // [8][2]
    float* s_w     = (float*)(smem + 2048);    // [1920] head weights

    const int b = blockIdx.x, tid = threadIdx.x;
    const int l = tid & 63, w = tid >> 6, g = l >> 4, l15 = l & 15;
    const int swzn = (l15 & 7) << 2;

    // ---- stage sumh1 = part0 + part1 (coalesced) into swizzled LDS
    for (int idx = tid; idx < 4096; idx += 1024) {
        const int row = idx >> 6, c4 = (idx & 63) * 4;
        const f32x4 v0 = *(const f32x4*)&sumh1[(size_t)b * 16384 + (size_t)idx * 4];
        const f32x4 v1 = *(const f32x4*)&sumh1[(size_t)NTOT * 256 +
                                               (size_t)b * 16384 + (size_t)idx * 4];
        *(f32x4*)&s_sumh1[row * 256 + (c4 ^ ((row & 7) << 2))] = v0 + v1;
    }
    __syncthreads();

    // ================= phase C =================  wave = (rt = w&3, cj = w>>2)
    const int rt = w & 3, cj = w >> 2;   // 4 row-tiles x 4 col-groups(4 chts)
    f32x4 acc2[4];
#pragma unroll
    for (int j = 0; j < 4; j++) acc2[j] = (f32x4){0.f, 0.f, 0.f, 0.f};

    for (int ks = 0; ks < 8; ks++) {
        const int row = rt * 16 + l15;
        const int cbk = ks * 32 + g * 8;
        const f32x4 a0 = *(const f32x4*)&s_sumh1[row * 256 + (cbk ^ swzn)];
        const f32x4 a1 = *(const f32x4*)&s_sumh1[row * 256 + ((cbk + 4) ^ swzn)];
        short8v Ahh, All;
        packfrag(a0, a1, Ahh, All);
#pragma unroll
        for (int j = 0; j < 4; j++) {
            const int base = (80 + ks * 16 + cj * 4 + j) * 1024 + l * 8;
            const short8v Bh = *(const short8v*)&frags[base];
            const short8v Bl = *(const short8v*)&frags[base + 512];
            acc2[j] = MFMA16(Ahh, Bh, acc2[j]);
            acc2[j] = MFMA16(Ahh, Bl, acc2[j]);
            acc2[j] = MFMA16(All, Bh, acc2[j]);
        }
    }

#pragma unroll
    for (int j = 0; j < 4; j++) {
        const int col = (cj * 4 + j) * 16 + l15;
        const float bb = 32.f * b2[col];
#pragma unroll
        for (int r = 0; r < 4; r++) {
            const int row = rt * 16 + g * 4 + r;
            s_agg[row * 256 + (col ^ ((row & 7) << 2))] = acc2[j][r] + bb;
        }
    }
    __syncthreads();   // all sumh1 reads done -> region reusable

    // ---- stage head weights into LDS (broadcast-read in D)
    for (int i = tid; i < 1920; i += 1024)
        s_w[i] = (i < 640) ? Wmu[i]
               : (i < 1280) ? Wsig[i - 640]
               : (i < 1600) ? Wmu2[i - 1280] : Wsig2[i - 1600];
    __syncthreads();

    // ================= phase D =================
    if (tid < 256) {
        const int n = tid >> 2, s = tid & 3;
        const float* Wp = s_w + (s & 1) * 640 + ((s >> 1) ? 320 : 0);
        const float* xr = x + (size_t)(b * 64 + n) * 64;
        const int sw = (n & 7) << 2;
        float z = 0.f;
#pragma unroll
        for (int kq = 0; kq < 16; kq++)
            z += dot4(*(const f32x4*)&xr[kq * 4], *(const f32x4*)&Wp[kq * 4]);
#pragma unroll 8
        for (int kq = 0; kq < 64; kq++)
            z += dot4(*(const f32x4*)&s_agg[n * 256 + ((kq * 4) ^ sw)],
                      *(const f32x4*)&Wp[64 + kq * 4]);
        s_su[n * 4 + s] = z;
    } else if (tid < 272) {
        const int j = (tid - 256) >> 1, s = tid & 1;
        const int n = 56 + j;
        const float* Wp = s_w + 1280 + (s ? 320 : 0);
        const float* xr = x + (size_t)(b * 64 + n) * 64;
        const int sw = (n & 7) << 2;
        float z = 0.f;
#pragma unroll
        for (int kq = 0; kq < 16; kq++)
            z += dot4(*(const f32x4*)&xr[kq * 4], *(const f32x4*)&Wp[kq * 4]);
#pragma unroll 8
        for (int kq = 0; kq < 64; kq++)
            z += dot4(*(const f32x4*)&s_agg[n * 256 + ((kq * 4) ^ sw)],
                      *(const f32x4*)&Wp[64 + kq * 4]);
        s_su2[j * 2 + s] = z;
    }
    __syncthreads();

    if (tid < 128) {
        const int e0 = edges[tid * 2], e1 = edges[tid * 2 + 1];
        const float a  = softplus_f(s_su[e0 * 4 + 0] + s_su[e1 * 4 + 2] + bmu[0])  + 1e-20f;
        const float be = softplus_f(s_su[e0 * 4 + 1] + s_su[e1 * 4 + 3] + bsig[0]) + 1e-20f;
        out[(size_t)b * 136 + tid] = a / (a + be) * high[tid];
    } else if (tid < 136) {
        const int j = tid - 128;
        const float a  = softplus_f(s_su2[j * 2 + 0] + bmu2[0])  + 1e-20f;
        const float be = softplus_f(s_su2[j * 2 + 1] + bsig2[0]) + 1e-20f;
        out[(size_t)b * 136 + tid] = a / (a + be) * high[128 + j];
    }
}

// ---------------------------------------------------------------------------
extern "C" void kernel_launch(void* const* d_in, const int* in_sizes, int n_in,
                              void* d_out, int out_size, void* d_ws, size_t ws_size,
                              hipStream_t stream) {
    const float* x     = (const float*)d_in[0];
    const int*   eidx  = (const int*)  d_in[1];
    const float* ea    = (const float*)d_in[2];
    const int*   edges = (const int*)  d_in[3];
    const float* high  = (const float*)d_in[4];
    const float* W1    = (const float*)d_in[5];
    const float* b1    = (const float*)d_in[6];
    const float* W2    = (const float*)d_in[7];
    const float* b2    = (const float*)d_in[8];
    const float* Wmu   = (const float*)d_in[9];
    const float* bmu   = (const float*)d_in[10];
    const float* Wsig  = (const float*)d_in[11];
    const float* bsig  = (const float*)d_in[12];
    const float* Wmu2  = (const float*)d_in[13];
    const float* bmu2  = (const float*)d_in[14];
    const float* Wsig2 = (const float*)d_in[15];
    const float* bsig2 = (const float*)d_in[16];
    float* out = (float*)d_out;

    // ws: sumh1 parts (2 x 16.8 MB) at base | frags (416 KB) at tail
    float* sumh1 = (float*)d_ws;
    const size_t frag_off = (ws_size - (size_t)208 * 2048) & ~(size_t)1023;
    unsigned short* frags = (unsigned short*)((char*)d_ws + frag_off);
    const int* dst = eidx + ETOT;

    hipLaunchKernelGGL(k_prep, dim3(208),    dim3(256),  0, stream, W1, W2, frags);
    hipLaunchKernelGGL(k_ab4,  dim3(1024),   dim3(512),  0, stream,
                       x, ea, dst, b1, frags, sumh1);
    hipLaunchKernelGGL(k_cd2,  dim3(BATCH_), dim3(1024), 0, stream,
                       x, sumh1, edges, high, frags, b2,
                       Wmu, bmu, Wsig, bsig, Wmu2, bmu2, Wsig2, bsig2, out);
}

// Round 12
// 83.864 us; speedup vs baseline: 1.0815x; 1.0815x over previous
//
#include <hip/hip_runtime.h>
#include <math.h>

#define BATCH_  256
#define NTOT    16384
#define ETOT    524288

typedef __attribute__((ext_vector_type(8))) short short8v;
typedef __attribute__((ext_vector_type(4))) float f32x4;

#define MFMA16(a,b,c) __builtin_amdgcn_mfma_f32_16x16x32_bf16((a),(b),(c),0,0,0)

__device__ __forceinline__ unsigned short f2bf(float f) {
    unsigned int x = __float_as_uint(f);
    return (unsigned short)((x + 0x7fffu + ((x >> 16) & 1u)) >> 16);
}
__device__ __forceinline__ float bf2f(unsigned short h) {
    return __uint_as_float(((unsigned int)h) << 16);
}
__device__ __forceinline__ float softplus_f(float v) {
    return v > 20.f ? v : log1pf(expf(v));
}
__device__ __forceinline__ float dot4(f32x4 a, f32x4 b) {
    float z = a[0] * b[0];
    z = fmaf(a[1], b[1], z);
    z = fmaf(a[2], b[2], z);
    z = fmaf(a[3], b[3], z);
    return z;
}
__device__ __forceinline__ void packfrag(f32x4 a, f32x4 q, short8v& hi, short8v& lo) {
    float v[8] = {a[0], a[1], a[2], a[3], q[0], q[1], q[2], q[3]};
#pragma unroll
    for (int j = 0; j < 8; j++) {
        const unsigned short h = f2bf(v[j]);
        hi[j] = (short)h;
        lo[j] = (short)f2bf(v[j] - bf2f(h));
    }
}
// hi-only pack via HW packed converter (RNE), 4 VALU for 8 values
__device__ __forceinline__ short8v cvthi8(f32x4 a, f32x4 q) {
    union { short8v s; unsigned int u[4]; } r;
    asm("v_cvt_pk_bf16_f32 %0, %1, %2" : "=v"(r.u[0]) : "v"(a[0]), "v"(a[1]));
    asm("v_cvt_pk_bf16_f32 %0, %1, %2" : "=v"(r.u[1]) : "v"(a[2]), "v"(a[3]));
    asm("v_cvt_pk_bf16_f32 %0, %1, %2" : "=v"(r.u[2]) : "v"(q[0]), "v"(q[1]));
    asm("v_cvt_pk_bf16_f32 %0, %1, %2" : "=v"(r.u[3]) : "v"(q[2]), "v"(q[3]));
    return r.s;
}

// ---------------------------------------------------------------------------
// K0: pre-pack split-bf16 (hi/lo) MFMA A-fragments of W1 (160x256, kt 0..4)
// and W2 (256x256, kt 0..7). Unit u = kt*16 + cht (W1: u 0..79; W2: u 80..207):
// frags[u*1024 + hl*512 + l*8 + j] = W[(kt*32+(l>>4)*8+j)*256 + cht*16+(l&15)]
// ---------------------------------------------------------------------------
__global__ __launch_bounds__(256) void k_prep(const float* __restrict__ W1,
                                              const float* __restrict__ W2,
                                              unsigned short* __restrict__ frags) {
    const int u = blockIdx.x;
    const float* S = (u < 80) ? W1 : W2;
    const int ul = (u < 80) ? u : (u - 80);
    const int rowbase = (ul >> 4) * 32;
    const int cht = ul & 15;
    for (int idx = threadIdx.x; idx < 512; idx += 256) {
        const int l = idx >> 3, j = idx & 7;
        const int row = rowbase + ((l >> 4) << 3) + j;
        const int col = cht * 16 + (l & 15);
        const float v = S[row * 256 + col];
        const unsigned short h = f2bf(v);
        frags[u * 1024 + idx]       = h;
        frags[u * 1024 + 512 + idx] = f2bf(v - bf2f(h));
    }
}

// ---------------------------------------------------------------------------
// K1: phases A+B per (batch, channel-half). Grid 512 (half = blockIdx>>8,
// so b and b+256 share an XCD/L2 for the duplicated ea reads).
// 512 thr, 8 waves. waves_per_eu(3): budget ~170 VGPR (state ~104, no
// spill; stays in 128-VGPR class = 4 waves/SIMD HW cap) while raising the
// residency hint 2->3 waves/EU. Session evidence: occupancy tracks this
// attribute's min value ((2)->~20%, (4)->33-41%); (3) is the untested
// point that should give residency without the 64-VGPR squeeze.
// Phase B: 8 chunks x 4 offsets, dbuf hi-only bf16 ea (cooperative,
// coalesced), 2-term split MFMA, swizzled-LDS xwb gather.
// LDS: s_xwb[64][128] f32 swz (32K) | s_ea [2][4][4][64][8] (32K) | dst 2K.
// ---------------------------------------------------------------------------
__global__ __launch_bounds__(512) __attribute__((amdgpu_waves_per_eu(3)))
void k_ab3(
    const float* __restrict__ x, const float* __restrict__ ea,
    const int* __restrict__ dst, const float* __restrict__ b1,
    const unsigned short* __restrict__ frags, float* __restrict__ sumh1)
{
    __shared__ __align__(16) unsigned char smem[67584];
    float*          s_xwb  = (float*)smem;                    // [64][128]
    unsigned short* s_ea   = (unsigned short*)(smem + 32768); // [2][4][4][64][8]
    unsigned char*  s_dstl = (unsigned char*)(smem + 65536);  // [2048]

    const int b = blockIdx.x & 255, half = blockIdx.x >> 8;
    const int tid = threadIdx.x;
    const int l = tid & 63, w = tid >> 6, g = l >> 4, l15 = l & 15;
    const int ng = w & 3, cqq = w >> 2;          // cqq in {0,1}
    const int node = ng * 16 + l15;
    const int swzn = (l15 & 7) << 2;

    // ---- dst staging (local ids, 1 byte per edge)
    for (int idx = tid; idx < 2048; idx += 512)
        s_dstl[idx] = (unsigned char)(dst[b * 2048 + idx] & 63);

    // ---- ea staging geometry: chunk = 4 offsets (128 floats/node).
    // thread -> (node sns = tid>>3, 16 consecutive floats at (tid&7)*16)
    const int sns = tid >> 3;
    const int so4 = (tid & 7) >> 1;        // offset-in-chunk 0..3
    const int sg0 = (tid & 1) * 2;         // first k-octet (g) of the 16 floats
    const int snl = sns & 15, ssng = sns >> 4;
    const float* seab = ea + (size_t)b * 65536 + (size_t)sns * 1024
                           + so4 * 32 + (tid & 1) * 16;

    // prologue: load chunk 0
    f32x4 L0 = *(const f32x4*)(seab);
    f32x4 L1 = *(const f32x4*)(seab + 4);
    f32x4 L2 = *(const f32x4*)(seab + 8);
    f32x4 L3 = *(const f32x4*)(seab + 12);

    // ================= phase A =================
    short8v Xh[2], Xl[2];
#pragma unroll
    for (int kt = 0; kt < 2; kt++) {
        const float* p = x + (size_t)(b * 64 + node) * 64 + kt * 32 + g * 8;
        packfrag(*(const f32x4*)p, *(const f32x4*)(p + 4), Xh[kt], Xl[kt]);
    }

    f32x4 xab1[4];
#pragma unroll
    for (int i = 0; i < 4; i++) {
        const int cht = half * 8 + cqq * 4 + i;
        f32x4 d = *(const f32x4*)&b1[cht * 16 + g * 4];   // C-init = b1
#pragma unroll
        for (int kt = 0; kt < 2; kt++) {
            const int base = (kt * 16 + cht) * 1024 + l * 8;
            const short8v Ahh = *(const short8v*)&frags[base];
            const short8v All = *(const short8v*)&frags[base + 512];
            d = MFMA16(All, Xh[kt], d);
            d = MFMA16(Ahh, Xl[kt], d);
            d = MFMA16(Ahh, Xh[kt], d);
        }
        xab1[i] = d;
    }

#pragma unroll
    for (int i = 0; i < 4; i++) {
        const int cht = half * 8 + cqq * 4 + i;
        f32x4 d = {0.f, 0.f, 0.f, 0.f};
#pragma unroll
        for (int kt = 0; kt < 2; kt++) {
            const int base = ((kt + 2) * 16 + cht) * 1024 + l * 8;
            const short8v Ahh = *(const short8v*)&frags[base];
            const short8v All = *(const short8v*)&frags[base + 512];
            d = MFMA16(All, Xh[kt], d);
            d = MFMA16(Ahh, Xl[kt], d);
            d = MFMA16(Ahh, Xh[kt], d);
        }
        *(f32x4*)&s_xwb[node * 128 + (((cqq * 4 + i) * 16 + g * 4) ^ swzn)] = d;
    }

    // W1c A-frags (units 64..79), register-cached
    short8v Ah[4], Al[4];
#pragma unroll
    for (int i = 0; i < 4; i++) {
        const int base = (64 + half * 8 + cqq * 4 + i) * 1024 + l * 8;
        Ah[i] = *(const short8v*)&frags[base];
        Al[i] = *(const short8v*)&frags[base + 512];
    }

    // stage chunk 0 into buf 0; issue chunk 1 loads
    {
        unsigned short* p = s_ea + ((0 * 4 + so4) * 4 + ssng) * 512;
        *(short8v*)&p[(sg0 * 16 + snl) * 8]       = cvthi8(L0, L1);
        *(short8v*)&p[((sg0 + 1) * 16 + snl) * 8] = cvthi8(L2, L3);
    }
    L0 = *(const f32x4*)(seab + 128);
    L1 = *(const f32x4*)(seab + 132);
    L2 = *(const f32x4*)(seab + 136);
    L3 = *(const f32x4*)(seab + 140);
    __syncthreads();   // xwb + dstl + chunk0 visible

    f32x4 acc[4];
#pragma unroll
    for (int i = 0; i < 4; i++) acc[i] = (f32x4){0.f, 0.f, 0.f, 0.f};

    // ================= phase B ================= (8 chunks x 4 offsets)
    for (int c = 0; c < 8; ++c) {
        if (c < 7) {   // stage next chunk into other buffer
            const int nb = (c + 1) & 1;
            unsigned short* p = s_ea + ((nb * 4 + so4) * 4 + ssng) * 512;
            *(short8v*)&p[(sg0 * 16 + snl) * 8]       = cvthi8(L0, L1);
            *(short8v*)&p[((sg0 + 1) * 16 + snl) * 8] = cvthi8(L2, L3);
            if (c < 6) {
                const float* q = seab + (size_t)(c + 2) * 128;
                L0 = *(const f32x4*)(q);
                L1 = *(const f32x4*)(q + 4);
                L2 = *(const f32x4*)(q + 8);
                L3 = *(const f32x4*)(q + 12);
            }
        }

        const int cb = c & 1;
        const unsigned int dw = ((const unsigned int*)s_dstl)[node * 8 + c];

#pragma unroll
        for (int ol = 0; ol < 4; ol++) {
            const short8v Bh =
                *(const short8v*)&s_ea[((cb * 4 + ol) * 4 + ng) * 512 + l * 8];
            const int d = (dw >> (ol * 8)) & 63;
            const int swz = (d & 7) << 2;

#pragma unroll
            for (int i = 0; i < 4; i++) {
                const int cbl = (cqq * 4 + i) * 16 + g * 4;
                const f32x4 wb = *(const f32x4*)&s_xwb[d * 128 + (cbl ^ swz)];
                f32x4 di = MFMA16(Al[i], Bh, xab1[i]);   // 2-term split
                di = MFMA16(Ah[i], Bh, di);
#pragma unroll
                for (int r = 0; r < 4; r++)
                    acc[i][r] += fmaxf(di[r] + wb[r], 0.f);
            }
        }
        __syncthreads();   // chunk consumed; next-buf stores visible
    }

    // write sumh1 (global, linear [node][256])
    const size_t grow = (size_t)b * 64 + node;
#pragma unroll
    for (int i = 0; i < 4; i++) {
        const int cg = (half * 8 + cqq * 4 + i) * 16 + g * 4;
        *(f32x4*)&sumh1[grow * 256 + cg] = acc[i];
    }
}

// ---------------------------------------------------------------------------
// K2: phases C+D per batch. 256 blocks, 1024 thr (16 waves).
// Stage sumh1 -> LDS swizzled; C: agg = sumh1@W2 + 32*b2 (16-wave split);
// stage head weights -> LDS; D: factored u/v dots; heads -> out.
// ---------------------------------------------------------------------------
__global__ __launch_bounds__(1024) __attribute__((amdgpu_waves_per_eu(2)))
void k_cd2(
    const float* __restrict__ x, const float* __restrict__ sumh1,
    const int* __restrict__ edges, const float* __restrict__ high,
    const unsigned short* __restrict__ frags, const float* __restrict__ b2,
    const float* __restrict__ Wmu,  const float* __restrict__ bmu,
    const float* __restrict__ Wsig, const float* __restrict__ bsig,
    const float* __restrict__ Wmu2, const float* __restrict__ bmu2,
    const float* __restrict__ Wsig2,const float* __restrict__ bsig2,
    float* __restrict__ out)
{
    __shared__ __align__(16) unsigned char smem[131072];
    float* s_sumh1 = (float*)smem;             // [64][256] swizzled
    float* s_agg   = (float*)(smem + 65536);   // [64][256] swizzled
    float* s_su    = (float*)smem;             // [64][4]   (after C)
    float* s_su2   = (float*)(smem + 1024);    // [8][2]
    float* s_w     = (float*)(smem + 2048);    // [1920] head weights

    const int b = blockIdx.x, tid = threadIdx.x;
    const int l = tid & 63, w = tid >> 6, g = l >> 4, l15 = l & 15;
    const int swzn = (l15 & 7) << 2;

    // ---- stage sumh1 (coalesced) into swizzled LDS
    for (int idx = tid; idx < 4096; idx += 1024) {
        const int row = idx >> 6, c4 = (idx & 63) * 4;
        const f32x4 v = *(const f32x4*)&sumh1[(size_t)b * 16384 + (size_t)idx * 4];
        *(f32x4*)&s_sumh1[row * 256 + (c4 ^ ((row & 7) << 2))] = v;
    }
    __syncthreads();

    // ================= phase C =================  wave = (rt = w&3, cj = w>>2)
    const int rt = w & 3, cj = w >> 2;   // 4 row-tiles x 4 col-groups(4 chts)
    f32x4 acc2[4];
#pragma unroll
    for (int j = 0; j < 4; j++) acc2[j] = (f32x4){0.f, 0.f, 0.f, 0.f};

    for (int ks = 0; ks < 8; ks++) {
        const int row = rt * 16 + l15;
        const int cbk = ks * 32 + g * 8;
        const f32x4 a0 = *(const f32x4*)&s_sumh1[row * 256 + (cbk ^ swzn)];
        const f32x4 a1 = *(const f32x4*)&s_sumh1[row * 256 + ((cbk + 4) ^ swzn)];
        short8v Ahh, All;
        packfrag(a0, a1, Ahh, All);
#pragma unroll
        for (int j = 0; j < 4; j++) {
            const int base = (80 + ks * 16 + cj * 4 + j) * 1024 + l * 8;
            const short8v Bh = *(const short8v*)&frags[base];
            const short8v Bl = *(const short8v*)&frags[base + 512];
            acc2[j] = MFMA16(Ahh, Bh, acc2[j]);
            acc2[j] = MFMA16(Ahh, Bl, acc2[j]);
            acc2[j] = MFMA16(All, Bh, acc2[j]);
        }
    }

#pragma unroll
    for (int j = 0; j < 4; j++) {
        const int col = (cj * 4 + j) * 16 + l15;
        const float bb = 32.f * b2[col];
#pragma unroll
        for (int r = 0; r < 4; r++) {
            const int row = rt * 16 + g * 4 + r;
            s_agg[row * 256 + (col ^ ((row & 7) << 2))] = acc2[j][r] + bb;
        }
    }
    __syncthreads();   // all sumh1 reads done -> region reusable

    // ---- stage head weights into LDS (broadcast-read in D)
    for (int i = tid; i < 1920; i += 1024)
        s_w[i] = (i < 640) ? Wmu[i]
               : (i < 1280) ? Wsig[i - 640]
               : (i < 1600) ? Wmu2[i - 1280] : Wsig2[i - 1600];
    __syncthreads();

    // ================= phase D =================
    if (tid < 256) {
        const int n = tid >> 2, s = tid & 3;
        const float* Wp = s_w + (s & 1) * 640 + ((s >> 1) ? 320 : 0);
        const float* xr = x + (size_t)(b * 64 + n) * 64;
        const int sw = (n & 7) << 2;
        float z = 0.f;
#pragma unroll
        for (int kq = 0; kq < 16; kq++)
            z += dot4(*(const f32x4*)&xr[kq * 4], *(const f32x4*)&Wp[kq * 4]);
#pragma unroll 8
        for (int kq = 0; kq < 64; kq++)
            z += dot4(*(const f32x4*)&s_agg[n * 256 + ((kq * 4) ^ sw)],
                      *(const f32x4*)&Wp[64 + kq * 4]);
        s_su[n * 4 + s] = z;
    } else if (tid < 272) {
        const int j = (tid - 256) >> 1, s = tid & 1;
        const int n = 56 + j;
        const float* Wp = s_w + 1280 + (s ? 320 : 0);
        const float* xr = x + (size_t)(b * 64 + n) * 64;
        const int sw = (n & 7) << 2;
        float z = 0.f;
#pragma unroll
        for (int kq = 0; kq < 16; kq++)
            z += dot4(*(const f32x4*)&xr[kq * 4], *(const f32x4*)&Wp[kq * 4]);
#pragma unroll 8
        for (int kq = 0; kq < 64; kq++)
            z += dot4(*(const f32x4*)&s_agg[n * 256 + ((kq * 4) ^ sw)],
                      *(const f32x4*)&Wp[64 + kq * 4]);
        s_su2[j * 2 + s] = z;
    }
    __syncthreads();

    if (tid < 128) {
        const int e0 = edges[tid * 2], e1 = edges[tid * 2 + 1];
        const float a  = softplus_f(s_su[e0 * 4 + 0] + s_su[e1 * 4 + 2] + bmu[0])  + 1e-20f;
        const float be = softplus_f(s_su[e0 * 4 + 1] + s_su[e1 * 4 + 3] + bsig[0]) + 1e-20f;
        out[(size_t)b * 136 + tid] = a / (a + be) * high[tid];
    } else if (tid < 136) {
        const int j = tid - 128;
        const float a  = softplus_f(s_su2[j * 2 + 0] + bmu2[0])  + 1e-20f;
        const float be = softplus_f(s_su2[j * 2 + 1] + bsig2[0]) + 1e-20f;
        out[(size_t)b * 136 + tid] = a / (a + be) * high[128 + j];
    }
}

// ---------------------------------------------------------------------------
extern "C" void kernel_launch(void* const* d_in, const int* in_sizes, int n_in,
                              void* d_out, int out_size, void* d_ws, size_t ws_size,
                              hipStream_t stream) {
    const float* x     = (const float*)d_in[0];
    const int*   eidx  = (const int*)  d_in[1];
    const float* ea    = (const float*)d_in[2];
    const int*   edges = (const int*)  d_in[3];
    const float* high  = (const float*)d_in[4];
    const float* W1    = (const float*)d_in[5];
    const float* b1    = (const float*)d_in[6];
    const float* W2    = (const float*)d_in[7];
    const float* b2    = (const float*)d_in[8];
    const float* Wmu   = (const float*)d_in[9];
    const float* bmu   = (const float*)d_in[10];
    const float* Wsig  = (const float*)d_in[11];
    const float* bsig  = (const float*)d_in[12];
    const float* Wmu2  = (const float*)d_in[13];
    const float* bmu2  = (const float*)d_in[14];
    const float* Wsig2 = (const float*)d_in[15];
    const float* bsig2 = (const float*)d_in[16];
    float* out = (float*)d_out;

    // ws: sumh1 (16384*256 f32 = 16.8 MB) at base | frags (416 KB) at tail
    float* sumh1 = (float*)d_ws;
    const size_t frag_off = (ws_size - (size_t)208 * 2048) & ~(size_t)1023;
    unsigned short* frags = (unsigned short*)((char*)d_ws + frag_off);
    const int* dst = eidx + ETOT;

    hipLaunchKernelGGL(k_prep, dim3(208),    dim3(256),  0, stream, W1, W2, frags);
    hipLaunchKernelGGL(k_ab3,  dim3(512),    dim3(512),  0, stream,
                       x, ea, dst, b1, frags, sumh1);
    hipLaunchKernelGGL(k_cd2,  dim3(BATCH_), dim3(1024), 0, stream,
                       x, sumh1, edges, high, frags, b2,
                       Wmu, bmu, Wsig, bsig, Wmu2, bmu2, Wsig2, bsig2, out);
}

// Round 13
// 69.586 us; speedup vs baseline: 1.3034x; 1.2052x over previous
//
#include <hip/hip_runtime.h>
#include <math.h>

#define BATCH_  256
#define NTOT    16384
#define ETOT    524288

typedef __attribute__((ext_vector_type(8))) short short8v;
typedef __attribute__((ext_vector_type(4))) float f32x4;

#define MFMA16(a,b,c) __builtin_amdgcn_mfma_f32_16x16x32_bf16((a),(b),(c),0,0,0)

__device__ __forceinline__ unsigned short f2bf(float f) {
    unsigned int x = __float_as_uint(f);
    return (unsigned short)((x + 0x7fffu + ((x >> 16) & 1u)) >> 16);
}
__device__ __forceinline__ float bf2f(unsigned short h) {
    return __uint_as_float(((unsigned int)h) << 16);
}
__device__ __forceinline__ float softplus_f(float v) {
    return v > 20.f ? v : log1pf(expf(v));
}
__device__ __forceinline__ float dot4(f32x4 a, f32x4 b) {
    float z = a[0] * b[0];
    z = fmaf(a[1], b[1], z);
    z = fmaf(a[2], b[2], z);
    z = fmaf(a[3], b[3], z);
    return z;
}
__device__ __forceinline__ void packfrag(f32x4 a, f32x4 q, short8v& hi, short8v& lo) {
    float v[8] = {a[0], a[1], a[2], a[3], q[0], q[1], q[2], q[3]};
#pragma unroll
    for (int j = 0; j < 8; j++) {
        const unsigned short h = f2bf(v[j]);
        hi[j] = (short)h;
        lo[j] = (short)f2bf(v[j] - bf2f(h));
    }
}
// hi-only pack via HW packed converter (RNE), 4 VALU for 8 values
__device__ __forceinline__ short8v cvthi8(f32x4 a, f32x4 q) {
    union { short8v s; unsigned int u[4]; } r;
    asm("v_cvt_pk_bf16_f32 %0, %1, %2" : "=v"(r.u[0]) : "v"(a[0]), "v"(a[1]));
    asm("v_cvt_pk_bf16_f32 %0, %1, %2" : "=v"(r.u[1]) : "v"(a[2]), "v"(a[3]));
    asm("v_cvt_pk_bf16_f32 %0, %1, %2" : "=v"(r.u[2]) : "v"(q[0]), "v"(q[1]));
    asm("v_cvt_pk_bf16_f32 %0, %1, %2" : "=v"(r.u[3]) : "v"(q[2]), "v"(q[3]));
    return r.s;
}

// ---------------------------------------------------------------------------
// K0: pre-pack split-bf16 (hi/lo) MFMA A-fragments of W1 (160x256, kt 0..4)
// and W2 (256x256, kt 0..7). Unit u = kt*16 + cht (W1: u 0..79; W2: u 80..207):
// frags[u*1024 + hl*512 + l*8 + j] = W[(kt*32+(l>>4)*8+j)*256 + cht*16+(l&15)]
// ---------------------------------------------------------------------------
__global__ __launch_bounds__(256) void k_prep(const float* __restrict__ W1,
                                              const float* __restrict__ W2,
                                              unsigned short* __restrict__ frags) {
    const int u = blockIdx.x;
    const float* S = (u < 80) ? W1 : W2;
    const int ul = (u < 80) ? u : (u - 80);
    const int rowbase = (ul >> 4) * 32;
    const int cht = ul & 15;
    for (int idx = threadIdx.x; idx < 512; idx += 256) {
        const int l = idx >> 3, j = idx & 7;
        const int row = rowbase + ((l >> 4) << 3) + j;
        const int col = cht * 16 + (l & 15);
        const float v = S[row * 256 + col];
        const unsigned short h = f2bf(v);
        frags[u * 1024 + idx]       = h;
        frags[u * 1024 + 512 + idx] = f2bf(v - bf2f(h));
    }
}

// ---------------------------------------------------------------------------
// K1: phases A+B per (batch, channel-half). Grid 512 (half = blockIdx>>8,
// so b and b+256 land on the same XCD -> shared ea reads hit L2).
// 512 thr, 8 waves, waves_per_eu(2): the ONLY attribute point that gives
// >64 VGPR without spill on this toolchain ((2)->104/no-spill,
// (3)->84/spill, (4)->64/heavy-spill — measured rounds 8-12).
// NEW this round: ea-staging bank-conflict fix. Old write slot sg0*16+snl
// put the 8 (so4,sg0) threads sharing snl&7 on one 4-bank group (8-way).
// Now: write slot ^= so4, read slot = l ^ ol — writes 2-way (free),
// reads a bijective lane permutation (conflict-free).
// LDS: s_xwb[64][128] f32 swz (32K) | s_ea [2][4][4][64][8] (32K) | dst 2K.
// ---------------------------------------------------------------------------
__global__ __launch_bounds__(512) __attribute__((amdgpu_waves_per_eu(2)))
void k_ab3(
    const float* __restrict__ x, const float* __restrict__ ea,
    const int* __restrict__ dst, const float* __restrict__ b1,
    const unsigned short* __restrict__ frags, float* __restrict__ sumh1)
{
    __shared__ __align__(16) unsigned char smem[67584];
    float*          s_xwb  = (float*)smem;                    // [64][128]
    unsigned short* s_ea   = (unsigned short*)(smem + 32768); // [2][4][4][64][8]
    unsigned char*  s_dstl = (unsigned char*)(smem + 65536);  // [2048]

    const int b = blockIdx.x & 255, half = blockIdx.x >> 8;
    const int tid = threadIdx.x;
    const int l = tid & 63, w = tid >> 6, g = l >> 4, l15 = l & 15;
    const int ng = w & 3, cqq = w >> 2;          // cqq in {0,1}
    const int node = ng * 16 + l15;
    const int swzn = (l15 & 7) << 2;

    // ---- dst staging (local ids, 1 byte per edge)
    for (int idx = tid; idx < 2048; idx += 512)
        s_dstl[idx] = (unsigned char)(dst[b * 2048 + idx] & 63);

    // ---- ea staging geometry: chunk = 4 offsets (128 floats/node).
    // thread -> (node sns = tid>>3, 16 consecutive floats at (tid&7)*16)
    const int sns = tid >> 3;
    const int so4 = (tid & 7) >> 1;        // offset-in-chunk 0..3
    const int sg0 = (tid & 1) * 2;         // first k-octet (g) of the 16 floats
    const int snl = sns & 15, ssng = sns >> 4;
    const float* seab = ea + (size_t)b * 65536 + (size_t)sns * 1024
                           + so4 * 32 + (tid & 1) * 16;

    // staging slots, XOR-swizzled by offset-slice (bank-conflict fix)
    const int slot0 = (sg0 * 16 + snl) ^ so4;
    const int slot1 = ((sg0 + 1) * 16 + snl) ^ so4;

    // prologue: load chunk 0
    f32x4 L0 = *(const f32x4*)(seab);
    f32x4 L1 = *(const f32x4*)(seab + 4);
    f32x4 L2 = *(const f32x4*)(seab + 8);
    f32x4 L3 = *(const f32x4*)(seab + 12);

    // ================= phase A =================
    short8v Xh[2], Xl[2];
#pragma unroll
    for (int kt = 0; kt < 2; kt++) {
        const float* p = x + (size_t)(b * 64 + node) * 64 + kt * 32 + g * 8;
        packfrag(*(const f32x4*)p, *(const f32x4*)(p + 4), Xh[kt], Xl[kt]);
    }

    f32x4 xab1[4];
#pragma unroll
    for (int i = 0; i < 4; i++) {
        const int cht = half * 8 + cqq * 4 + i;
        f32x4 d = *(const f32x4*)&b1[cht * 16 + g * 4];   // C-init = b1
#pragma unroll
        for (int kt = 0; kt < 2; kt++) {
            const int base = (kt * 16 + cht) * 1024 + l * 8;
            const short8v Ahh = *(const short8v*)&frags[base];
            const short8v All = *(const short8v*)&frags[base + 512];
            d = MFMA16(All, Xh[kt], d);
            d = MFMA16(Ahh, Xl[kt], d);
            d = MFMA16(Ahh, Xh[kt], d);
        }
        xab1[i] = d;
    }

#pragma unroll
    for (int i = 0; i < 4; i++) {
        const int cht = half * 8 + cqq * 4 + i;
        f32x4 d = {0.f, 0.f, 0.f, 0.f};
#pragma unroll
        for (int kt = 0; kt < 2; kt++) {
            const int base = ((kt + 2) * 16 + cht) * 1024 + l * 8;
            const short8v Ahh = *(const short8v*)&frags[base];
            const short8v All = *(const short8v*)&frags[base + 512];
            d = MFMA16(All, Xh[kt], d);
            d = MFMA16(Ahh, Xl[kt], d);
            d = MFMA16(Ahh, Xh[kt], d);
        }
        *(f32x4*)&s_xwb[node * 128 + (((cqq * 4 + i) * 16 + g * 4) ^ swzn)] = d;
    }

    // W1c A-frags (units 64..79), register-cached
    short8v Ah[4], Al[4];
#pragma unroll
    for (int i = 0; i < 4; i++) {
        const int base = (64 + half * 8 + cqq * 4 + i) * 1024 + l * 8;
        Ah[i] = *(const short8v*)&frags[base];
        Al[i] = *(const short8v*)&frags[base + 512];
    }

    // stage chunk 0 into buf 0; issue chunk 1 loads
    {
        unsigned short* p = s_ea + ((0 * 4 + so4) * 4 + ssng) * 512;
        *(short8v*)&p[slot0 * 8] = cvthi8(L0, L1);
        *(short8v*)&p[slot1 * 8] = cvthi8(L2, L3);
    }
    L0 = *(const f32x4*)(seab + 128);
    L1 = *(const f32x4*)(seab + 132);
    L2 = *(const f32x4*)(seab + 136);
    L3 = *(const f32x4*)(seab + 140);
    __syncthreads();   // xwb + dstl + chunk0 visible

    f32x4 acc[4];
#pragma unroll
    for (int i = 0; i < 4; i++) acc[i] = (f32x4){0.f, 0.f, 0.f, 0.f};

    // ================= phase B ================= (8 chunks x 4 offsets)
    for (int c = 0; c < 8; ++c) {
        if (c < 7) {   // stage next chunk into other buffer
            const int nb = (c + 1) & 1;
            unsigned short* p = s_ea + ((nb * 4 + so4) * 4 + ssng) * 512;
            *(short8v*)&p[slot0 * 8] = cvthi8(L0, L1);
            *(short8v*)&p[slot1 * 8] = cvthi8(L2, L3);
            if (c < 6) {
                const float* q = seab + (size_t)(c + 2) * 128;
                L0 = *(const f32x4*)(q);
                L1 = *(const f32x4*)(q + 4);
                L2 = *(const f32x4*)(q + 8);
                L3 = *(const f32x4*)(q + 12);
            }
        }

        const int cb = c & 1;
        const unsigned int dw = ((const unsigned int*)s_dstl)[node * 8 + c];

#pragma unroll
        for (int ol = 0; ol < 4; ol++) {
            const short8v Bh =
                *(const short8v*)&s_ea[((cb * 4 + ol) * 4 + ng) * 512 + (l ^ ol) * 8];
            const int d = (dw >> (ol * 8)) & 63;
            const int swz = (d & 7) << 2;

#pragma unroll
            for (int i = 0; i < 4; i++) {
                const int cbl = (cqq * 4 + i) * 16 + g * 4;
                const f32x4 wb = *(const f32x4*)&s_xwb[d * 128 + (cbl ^ swz)];
                f32x4 di = MFMA16(Al[i], Bh, xab1[i]);   // 2-term split
                di = MFMA16(Ah[i], Bh, di);
#pragma unroll
                for (int r = 0; r < 4; r++)
                    acc[i][r] += fmaxf(di[r] + wb[r], 0.f);
            }
        }
        __syncthreads();   // chunk consumed; next-buf stores visible
    }

    // write sumh1 (global, linear [node][256])
    const size_t grow = (size_t)b * 64 + node;
#pragma unroll
    for (int i = 0; i < 4; i++) {
        const int cg = (half * 8 + cqq * 4 + i) * 16 + g * 4;
        *(f32x4*)&sumh1[grow * 256 + cg] = acc[i];
    }
}

// ---------------------------------------------------------------------------
// K2: phases C+D per batch. 256 blocks, 1024 thr (16 waves).
// Stage sumh1 -> LDS swizzled; C: agg = sumh1@W2 + 32*b2 (16-wave split);
// stage head weights -> LDS; D: factored u/v dots; heads -> out.
// ---------------------------------------------------------------------------
__global__ __launch_bounds__(1024) __attribute__((amdgpu_waves_per_eu(2)))
void k_cd2(
    const float* __restrict__ x, const float* __restrict__ sumh1,
    const int* __restrict__ edges, const float* __restrict__ high,
    const unsigned short* __restrict__ frags, const float* __restrict__ b2,
    const float* __restrict__ Wmu,  const float* __restrict__ bmu,
    const float* __restrict__ Wsig, const float* __restrict__ bsig,
    const float* __restrict__ Wmu2, const float* __restrict__ bmu2,
    const float* __restrict__ Wsig2,const float* __restrict__ bsig2,
    float* __restrict__ out)
{
    __shared__ __align__(16) unsigned char smem[131072];
    float* s_sumh1 = (float*)smem;             // [64][256] swizzled
    float* s_agg   = (float*)(smem + 65536);   // [64][256] swizzled
    float* s_su    = (float*)smem;             // [64][4]   (after C)
    float* s_su2   = (float*)(smem + 1024);    // [8][2]
    float* s_w     = (float*)(smem + 2048);    // [1920] head weights

    const int b = blockIdx.x, tid = threadIdx.x;
    const int l = tid & 63, w = tid >> 6, g = l >> 4, l15 = l & 15;
    const int swzn = (l15 & 7) << 2;

    // ---- stage sumh1 (coalesced) into swizzled LDS
    for (int idx = tid; idx < 4096; idx += 1024) {
        const int row = idx >> 6, c4 = (idx & 63) * 4;
        const f32x4 v = *(const f32x4*)&sumh1[(size_t)b * 16384 + (size_t)idx * 4];
        *(f32x4*)&s_sumh1[row * 256 + (c4 ^ ((row & 7) << 2))] = v;
    }
    __syncthreads();

    // ================= phase C =================  wave = (rt = w&3, cj = w>>2)
    const int rt = w & 3, cj = w >> 2;   // 4 row-tiles x 4 col-groups(4 chts)
    f32x4 acc2[4];
#pragma unroll
    for (int j = 0; j < 4; j++) acc2[j] = (f32x4){0.f, 0.f, 0.f, 0.f};

    for (int ks = 0; ks < 8; ks++) {
        const int row = rt * 16 + l15;
        const int cbk = ks * 32 + g * 8;
        const f32x4 a0 = *(const f32x4*)&s_sumh1[row * 256 + (cbk ^ swzn)];
        const f32x4 a1 = *(const f32x4*)&s_sumh1[row * 256 + ((cbk + 4) ^ swzn)];
        short8v Ahh, All;
        packfrag(a0, a1, Ahh, All);
#pragma unroll
        for (int j = 0; j < 4; j++) {
            const int base = (80 + ks * 16 + cj * 4 + j) * 1024 + l * 8;
            const short8v Bh = *(const short8v*)&frags[base];
            const short8v Bl = *(const short8v*)&frags[base + 512];
            acc2[j] = MFMA16(Ahh, Bh, acc2[j]);
            acc2[j] = MFMA16(Ahh, Bl, acc2[j]);
            acc2[j] = MFMA16(All, Bh, acc2[j]);
        }
    }

#pragma unroll
    for (int j = 0; j < 4; j++) {
        const int col = (cj * 4 + j) * 16 + l15;
        const float bb = 32.f * b2[col];
#pragma unroll
        for (int r = 0; r < 4; r++) {
            const int row = rt * 16 + g * 4 + r;
            s_agg[row * 256 + (col ^ ((row & 7) << 2))] = acc2[j][r] + bb;
        }
    }
    __syncthreads();   // all sumh1 reads done -> region reusable

    // ---- stage head weights into LDS (broadcast-read in D)
    for (int i = tid; i < 1920; i += 1024)
        s_w[i] = (i < 640) ? Wmu[i]
               : (i < 1280) ? Wsig[i - 640]
               : (i < 1600) ? Wmu2[i - 1280] : Wsig2[i - 1600];
    __syncthreads();

    // ================= phase D =================
    if (tid < 256) {
        const int n = tid >> 2, s = tid & 3;
        const float* Wp = s_w + (s & 1) * 640 + ((s >> 1) ? 320 : 0);
        const float* xr = x + (size_t)(b * 64 + n) * 64;
        const int sw = (n & 7) << 2;
        float z = 0.f;
#pragma unroll
        for (int kq = 0; kq < 16; kq++)
            z += dot4(*(const f32x4*)&xr[kq * 4], *(const f32x4*)&Wp[kq * 4]);
#pragma unroll 8
        for (int kq = 0; kq < 64; kq++)
            z += dot4(*(const f32x4*)&s_agg[n * 256 + ((kq * 4) ^ sw)],
                      *(const f32x4*)&Wp[64 + kq * 4]);
        s_su[n * 4 + s] = z;
    } else if (tid < 272) {
        const int j = (tid - 256) >> 1, s = tid & 1;
        const int n = 56 + j;
        const float* Wp = s_w + 1280 + (s ? 320 : 0);
        const float* xr = x + (size_t)(b * 64 + n) * 64;
        const int sw = (n & 7) << 2;
        float z = 0.f;
#pragma unroll
        for (int kq = 0; kq < 16; kq++)
            z += dot4(*(const f32x4*)&xr[kq * 4], *(const f32x4*)&Wp[kq * 4]);
#pragma unroll 8
        for (int kq = 0; kq < 64; kq++)
            z += dot4(*(const f32x4*)&s_agg[n * 256 + ((kq * 4) ^ sw)],
                      *(const f32x4*)&Wp[64 + kq * 4]);
        s_su2[j * 2 + s] = z;
    }
    __syncthreads();

    if (tid < 128) {
        const int e0 = edges[tid * 2], e1 = edges[tid * 2 + 1];
        const float a  = softplus_f(s_su[e0 * 4 + 0] + s_su[e1 * 4 + 2] + bmu[0])  + 1e-20f;
        const float be = softplus_f(s_su[e0 * 4 + 1] + s_su[e1 * 4 + 3] + bsig[0]) + 1e-20f;
        out[(size_t)b * 136 + tid] = a / (a + be) * high[tid];
    } else if (tid < 136) {
        const int j = tid - 128;
        const float a  = softplus_f(s_su2[j * 2 + 0] + bmu2[0])  + 1e-20f;
        const float be = softplus_f(s_su2[j * 2 + 1] + bsig2[0]) + 1e-20f;
        out[(size_t)b * 136 + tid] = a / (a + be) * high[128 + j];
    }
}

// ---------------------------------------------------------------------------
extern "C" void kernel_launch(void* const* d_in, const int* in_sizes, int n_in,
                              void* d_out, int out_size, void* d_ws, size_t ws_size,
                              hipStream_t stream) {
    const float* x     = (const float*)d_in[0];
    const int*   eidx  = (const int*)  d_in[1];
    const float* ea    = (const float*)d_in[2];
    const int*   edges = (const int*)  d_in[3];
    const float* high  = (const float*)d_in[4];
    const float* W1    = (const float*)d_in[5];
    const float* b1    = (const float*)d_in[6];
    const float* W2    = (const float*)d_in[7];
    const float* b2    = (const float*)d_in[8];
    const float* Wmu   = (const float*)d_in[9];
    const float* bmu   = (const float*)d_in[10];
    const float* Wsig  = (const float*)d_in[11];
    const float* bsig  = (const float*)d_in[12];
    const float* Wmu2  = (const float*)d_in[13];
    const float* bmu2  = (const float*)d_in[14];
    const float* Wsig2 = (const float*)d_in[15];
    const float* bsig2 = (const float*)d_in[16];
    float* out = (float*)d_out;

    // ws: sumh1 (16384*256 f32 = 16.8 MB) at base | frags (416 KB) at tail
    float* sumh1 = (float*)d_ws;
    const size_t frag_off = (ws_size - (size_t)208 * 2048) & ~(size_t)1023;
    unsigned short* frags = (unsigned short*)((char*)d_ws + frag_off);
    const int* dst = eidx + ETOT;

    hipLaunchKernelGGL(k_prep, dim3(208),    dim3(256),  0, stream, W1, W2, frags);
    hipLaunchKernelGGL(k_ab3,  dim3(512),    dim3(512),  0, stream,
                       x, ea, dst, b1, frags, sumh1);
    hipLaunchKernelGGL(k_cd2,  dim3(BATCH_), dim3(1024), 0, stream,
                       x, sumh1, edges, high, frags, b2,
                       Wmu, bmu, Wsig, bsig, Wmu2, bmu2, Wsig2, bsig2, out);
}